// Round 1
// baseline (280.151 us; speedup 1.0000x reference)
//
#include <hip/hip_runtime.h>

// x        [64, 524288] f32 | idx_feat [4096,256] f32 | weight [64,256] f32
// bias     [64] f32         | pred_cate [4096] i32    | pred_score [4096] f32
// out (f32 concat): seg_pred [53*524288], unique_cate [53], fused_score [53]

#define KK   4096
#define CIN  256
#define CC   64
#define HW   524288   // 512*1024
#define HW4  (HW / 4) // float4 columns
#define UU   53
#define FWS  56       // fwt row stride (53 padded)

#define CHUNKS 32
#define KPC    (KK / CHUNKS)   // 128 rows per chunk

// ws layout (floats)
#define WS_GSUM 0                    // [53][256] class feature sums (atomic)
#define WS_GSC  (UU * CIN)           // 13568: [53] score sums (atomic)
#define WS_GCNT (WS_GSC + 64)        // 13632: [53] counts (atomic)
#define WS_FWT  (WS_GCNT + 64)       // 13696: fw TRANSPOSED [64][FWS]
#define WS_ZERO WS_FWT               // floats to zero

typedef float f4 __attribute__((ext_vector_type(4)));

// ---------------------------------------------------------------------------
// Stage 1: segment feature sums + score/count, fused. Grid (53 x 32 chunks);
// each block scans 128 pred_cate entries (uniform -> s_load batches),
// register-accumulates matching rows (thread owns cin=tid), then one
// atomicAdd per thread (32 adds/address; reorder noise ~1e-7 rel).
// Score/count accumulated uniformly by all threads; lanes 0/1 commit.
// ---------------------------------------------------------------------------
__global__ __launch_bounds__(256)
void accum_kernel(const float* __restrict__ idx_feat,
                  const int*   __restrict__ pred_cate,
                  const float* __restrict__ pred_score,
                  float* __restrict__ ws)
{
    const int u   = blockIdx.x;
    const int ch  = blockIdx.y;
    const int tid = threadIdx.x;

    float acc = 0.0f, sc = 0.0f, cnt = 0.0f;
    const int k0 = ch * KPC;
    #pragma unroll 8
    for (int k = k0; k < k0 + KPC; ++k) {
        if (pred_cate[k] == u) {                      // uniform branch
            acc += idx_feat[(size_t)k * CIN + tid];   // coalesced row load
            sc  += pred_score[k];
            cnt += 1.0f;
        }
    }
    atomicAdd(&ws[WS_GSUM + u * CIN + tid], acc);
    if (tid == 0) atomicAdd(&ws[WS_GSC  + u], sc);
    if (tid == 1) atomicAdd(&ws[WS_GCNT + u], cnt);
}

// ---------------------------------------------------------------------------
// Stage 2: project class means through weight/bias; write fw TRANSPOSED
// ([c][u], stride FWS) so seg reads 53 CONSECUTIVE floats per channel
// (batched s_load_dwordx8/16). Emits unique_cate + fused_score.
// ---------------------------------------------------------------------------
__global__ __launch_bounds__(64)
void project_kernel(const float* __restrict__ ws_ro,
                    const float* __restrict__ weight,
                    const float* __restrict__ bias,
                    float* __restrict__ ws,
                    float* __restrict__ out)
{
    const int u = blockIdx.x;
    const int c = threadIdx.x;
    const float inv = 1.0f / ws_ro[WS_GCNT + u];

    float d = 0.0f;
    #pragma unroll 8
    for (int i = 0; i < CIN; ++i)
        d = fmaf(ws_ro[WS_GSUM + u * CIN + i], weight[(size_t)c * CIN + i], d);
    ws[WS_FWT + c * FWS + u] = d * inv + bias[c];

    if (c == 0) {
        out[(size_t)UU * HW + u]      = (float)u;                 // unique_cate
        out[(size_t)UU * HW + UU + u] = ws_ro[WS_GSC + u] * inv;  // fused_score
    }
}

// ---------------------------------------------------------------------------
// Stage 3: seg_pred = fw [53,64] @ x [64, HW].
// Thread owns one float4 column; x read EXACTLY once (FETCH ~134 MB); all 53
// float4 accumulators in registers (212 VGPR, launch_bounds(256,2) -> 2
// waves/SIMD). x/out are pure streams -> non-temporal to bypass L2.
// Per c-iter: 1 nt dwordx4 load + 53 consecutive uniform fwt floats (sK$)
// + 212 FMA. Floors: mem 245 MB @6.3 TB/s = 39 us; VALU 22.6 us.
// ---------------------------------------------------------------------------
__global__ __launch_bounds__(256, 2)
void seg_pred_kernel(const float* __restrict__ x,
                     const float* __restrict__ ws,
                     float* __restrict__ out)
{
    const int j = blockIdx.x * 256 + threadIdx.x;   // float4 column index
    const f4* x4   = (const f4*)x;
    f4*       out4 = (f4*)out;
    const float* fwt = ws + WS_FWT;

    f4 acc[UU];
    #pragma unroll
    for (int u = 0; u < UU; ++u) acc[u] = (f4)0.0f;

    #pragma unroll 2
    for (int c = 0; c < CC; ++c) {
        const f4 xv = __builtin_nontemporal_load(&x4[(size_t)c * HW4 + j]);
        #pragma unroll
        for (int u = 0; u < UU; ++u) {
            const float w = fwt[c * FWS + u];        // uniform, consecutive
            acc[u].x = fmaf(w, xv.x, acc[u].x);
            acc[u].y = fmaf(w, xv.y, acc[u].y);
            acc[u].z = fmaf(w, xv.z, acc[u].z);
            acc[u].w = fmaf(w, xv.w, acc[u].w);
        }
    }

    #pragma unroll
    for (int u = 0; u < UU; ++u)
        __builtin_nontemporal_store(acc[u], &out4[(size_t)u * HW4 + j]);
}

extern "C" void kernel_launch(void* const* d_in, const int* in_sizes, int n_in,
                              void* d_out, int out_size, void* d_ws, size_t ws_size,
                              hipStream_t stream)
{
    const float* x          = (const float*)d_in[0];
    const float* idx_feat   = (const float*)d_in[1];
    const float* weight     = (const float*)d_in[2];
    const float* bias       = (const float*)d_in[3];
    const int*   pred_cate  = (const int*)d_in[4];
    const float* pred_score = (const float*)d_in[5];

    float* out = (float*)d_out;
    float* ws  = (float*)d_ws;

    // zero the atomic accumulator region (ws re-poisoned 0xAA each call)
    hipMemsetAsync(ws, 0, (size_t)WS_ZERO * sizeof(float), stream);

    accum_kernel<<<dim3(UU, CHUNKS), 256, 0, stream>>>(idx_feat, pred_cate,
                                                       pred_score, ws);
    project_kernel<<<UU, 64, 0, stream>>>(ws, weight, bias, ws, out);
    seg_pred_kernel<<<HW4 / 256, 256, 0, stream>>>(x, ws, out);  // 512 blocks
}

// Round 2
// 279.445 us; speedup vs baseline: 1.0025x; 1.0025x over previous
//
#include <hip/hip_runtime.h>

// x        [64, 524288] f32 | idx_feat [4096,256] f32 | weight [64,256] f32
// bias     [64] f32         | pred_cate [4096] i32    | pred_score [4096] f32
// out (f32 concat): seg_pred [53*524288], unique_cate [53], fused_score [53]

#define KK   4096
#define CIN  256
#define CC   64
#define HW   524288   // 512*1024
#define HW4  (HW / 4) // float4 columns
#define UU   53
#define FWS  56       // fwt row stride (53 padded)

// ws layout (floats) — only fwt now; no atomics, no memset needed
#define WS_FWT 0      // fw TRANSPOSED [64][FWS]

typedef float f4 __attribute__((ext_vector_type(4)));

// ---------------------------------------------------------------------------
// Fused stages 1+2: one block per class u (53 blocks, 256 threads).
// Per-class independence: fw[:,u] depends only on class u's feature sums.
//  Phase A: parallel scan of pred_cate (16 iters/thread, coalesced) ->
//           compact matching row indices into LDS list (count = nmatch),
//           accumulate pred_score locally; wave shuffle-reduce.
//  Phase B: feature sums — thread owns cin=tid, loops over the ~77-entry
//           list (uniform LDS broadcast) with coalesced 1KB row loads.
//           Each idx_feat row still read exactly once device-wide.
//  Phase C: project through weight/bias: tid=(c<<2)|q, each q-group sums
//           64 of the 256 inputs, 2x shfl_xor reduce, q==0 writes
//           fwt[c][u] (transposed, stride FWS). tid 0 emits unique_cate
//           and fused_score.
// Replaces: hipMemsetAsync + accum_kernel (global atomics) + project_kernel.
// ---------------------------------------------------------------------------
__global__ __launch_bounds__(256)
void fused12_kernel(const float* __restrict__ idx_feat,
                    const int*   __restrict__ pred_cate,
                    const float* __restrict__ pred_score,
                    const float* __restrict__ weight,
                    const float* __restrict__ bias,
                    float* __restrict__ ws,
                    float* __restrict__ out)
{
    const int u   = blockIdx.x;
    const int tid = threadIdx.x;

    __shared__ int   list[128];    // max count per class is 78 (4096 = 53*77+15)
    __shared__ int   nmatch;
    __shared__ float sumf[CIN];    // per-cin class feature sums
    __shared__ float wsum[4];      // per-wave score partials

    if (tid == 0) nmatch = 0;
    __syncthreads();

    // ---- Phase A: scan + compact + score ----
    float sc = 0.0f;
    #pragma unroll
    for (int k = tid; k < KK; k += 256) {       // coalesced int loads
        if (pred_cate[k] == u) {
            int pos = atomicAdd(&nmatch, 1);    // LDS atomic, ~77/block total
            list[pos] = k;
            sc += pred_score[k];
        }
    }
    // wave-reduce score (64 lanes)
    #pragma unroll
    for (int off = 32; off > 0; off >>= 1) sc += __shfl_down(sc, off);
    if ((tid & 63) == 0) wsum[tid >> 6] = sc;
    __syncthreads();                            // list + wsum complete

    // ---- Phase B: feature sums, thread owns cin = tid ----
    const int n = nmatch;                       // uniform
    float acc = 0.0f;
    #pragma unroll 4
    for (int m = 0; m < n; ++m) {
        const int k = list[m];                  // uniform LDS broadcast
        acc += idx_feat[(size_t)k * CIN + tid]; // coalesced row load
    }
    sumf[tid] = acc;
    __syncthreads();

    // ---- Phase C: fw[:,u] = (weight @ mean_u) + bias, transposed store ----
    const float inv = 1.0f / (float)n;
    const int c = tid >> 2;                     // output channel 0..63
    const int q = tid & 3;                      // quarter of the 256-dot
    float d = 0.0f;
    const int i0 = q * 64;
    #pragma unroll 8
    for (int i = 0; i < 64; ++i)
        d = fmaf(sumf[i0 + i], weight[(size_t)c * CIN + i0 + i], d);
    d += __shfl_xor(d, 1);
    d += __shfl_xor(d, 2);                      // q-group of 4 summed
    if (q == 0)
        ws[WS_FWT + c * FWS + u] = d * inv + bias[c];

    if (tid == 0) {
        out[(size_t)UU * HW + u]      = (float)u;                       // unique_cate
        out[(size_t)UU * HW + UU + u] = (wsum[0] + wsum[1] + wsum[2] + wsum[3]) * inv; // fused_score
    }
}

// ---------------------------------------------------------------------------
// Stage 3 (UNCHANGED, verified): seg_pred = fw [53,64] @ x [64, HW].
// Thread owns one float4 column; x read EXACTLY once (FETCH ~134 MB); all 53
// float4 accumulators in registers (212 VGPR, launch_bounds(256,2) -> 2
// waves/SIMD). x/out are pure streams -> non-temporal to bypass L2.
// Per c-iter: 1 nt dwordx4 load + 53 consecutive uniform fwt floats (sK$)
// + 212 FMA. Floors: mem 245 MB @6.3 TB/s = 39 us; VALU 22.6 us.
// ---------------------------------------------------------------------------
__global__ __launch_bounds__(256, 2)
void seg_pred_kernel(const float* __restrict__ x,
                     const float* __restrict__ ws,
                     float* __restrict__ out)
{
    const int j = blockIdx.x * 256 + threadIdx.x;   // float4 column index
    const f4* x4   = (const f4*)x;
    f4*       out4 = (f4*)out;
    const float* fwt = ws + WS_FWT;

    f4 acc[UU];
    #pragma unroll
    for (int u = 0; u < UU; ++u) acc[u] = (f4)0.0f;

    #pragma unroll 2
    for (int c = 0; c < CC; ++c) {
        const f4 xv = __builtin_nontemporal_load(&x4[(size_t)c * HW4 + j]);
        #pragma unroll
        for (int u = 0; u < UU; ++u) {
            const float w = fwt[c * FWS + u];        // uniform, consecutive
            acc[u].x = fmaf(w, xv.x, acc[u].x);
            acc[u].y = fmaf(w, xv.y, acc[u].y);
            acc[u].z = fmaf(w, xv.z, acc[u].z);
            acc[u].w = fmaf(w, xv.w, acc[u].w);
        }
    }

    #pragma unroll
    for (int u = 0; u < UU; ++u)
        __builtin_nontemporal_store(acc[u], &out4[(size_t)u * HW4 + j]);
}

extern "C" void kernel_launch(void* const* d_in, const int* in_sizes, int n_in,
                              void* d_out, int out_size, void* d_ws, size_t ws_size,
                              hipStream_t stream)
{
    const float* x          = (const float*)d_in[0];
    const float* idx_feat   = (const float*)d_in[1];
    const float* weight     = (const float*)d_in[2];
    const float* bias       = (const float*)d_in[3];
    const int*   pred_cate  = (const int*)d_in[4];
    const float* pred_score = (const float*)d_in[5];

    float* out = (float*)d_out;
    float* ws  = (float*)d_ws;

    fused12_kernel<<<UU, 256, 0, stream>>>(idx_feat, pred_cate, pred_score,
                                           weight, bias, ws, out);
    seg_pred_kernel<<<HW4 / 256, 256, 0, stream>>>(x, ws, out);  // 512 blocks
}